// Round 14
// baseline (2517.737 us; speedup 1.0000x reference)
//
#include <hip/hip_runtime.h>

#define HN    128
#define NPG   32
#define NT    512
#define NTEAM 4          // teams per block, 2 waves each
#define SPS   16         // graph-pairs per team (serial)
#define SX    132        // padded floats per node row (528 B = 33*16, 16B aligned)
#define TILE  (NPG * SX)

typedef float f4 __attribute__((ext_vector_type(4)));
typedef float f2 __attribute__((ext_vector_type(2)));

__device__ __forceinline__ float tanh_fast(float v) {
  // tanh(v) = 1 - 2/(1+exp(2v)); saturates gracefully at +-1
  return 1.0f - 2.0f / (1.0f + __expf(2.0f * v));
}

__global__ __launch_bounds__(NT, 2) void gib_main(
    const float* __restrict__ x,  const float* __restrict__ W1,
    const float* __restrict__ b1, const float* __restrict__ W2,
    const float* __restrict__ b2, const float* __restrict__ gn,
    const float* __restrict__ un, const int* __restrict__ ei,
    float* __restrict__ out, float* __restrict__ ws,
    int G, long E, int epg)
{
  const int t    = threadIdx.x;
  const int wv   = t >> 6;
  const int l    = t & 63;
  const int tm   = wv >> 1;     // team 0..3
  const int role = wv & 1;      // column half (cols role*64 .. +63)
  const int gh   = l >> 5;      // graph within the team's pair
  const int n    = l & 31;      // node index / feature-pair index

  __shared__ __align__(16) float xt[2 * NTEAM][TILE];   // 135 KB
  __shared__ f2    zx[NTEAM][2][64];                    // z partials
  __shared__ float lp_s[NTEAM][2][NPG], a0_s[NTEAM][2][NPG];
  __shared__ float part[NTEAM][2][2][2];                // [team][role][gh][{tv,rr}]

  const long GL  = (long)G * HN;
  const float b20 = b2[0], b21 = b2[1];
  const int  cb  = role * 64;

  const long gbase = ((long)blockIdx.x * NTEAM + tm) * (2 * SPS);

  for (int si = 0; si < SPS; ++si) {
    const long gA = gbase + 2 * si;
    const long g  = gA + gh;        // lane's graph
    const long nb = g * NPG;

    // ---- stage this wave's graph tile (pad+XOR swizzle); transient 64 VGPR ----
    {
      const float* src = x + (gA + role) * NPG * HN;
      float* dstp = &xt[tm * 2 + role][0];
      f4 tmp[16];
      #pragma unroll
      for (int r = 0; r < 16; ++r) {
        int idx = r * 64 + l;
        int node = idx >> 5, p = idx & 31, c = p ^ (node & 7);
        tmp[r] = *(const f4*)(src + node * HN + c * 4);
      }
      #pragma unroll
      for (int r = 0; r < 16; ++r) {
        int idx = r * 64 + l;
        int node = idx >> 5, p = idx & 31;
        *(f4*)&dstp[node * SX + p * 4] = tmp[r];
      }
    }
    __syncthreads();   // B1: tiles ready

    // ---- MLP: lane's node, 64 cols; x from LDS, W1/b1/W2 wave-uniform ----
    f2 zp = {0.f, 0.f};
    {
      const float* xb = &xt[tm * 2 + gh][n * SX];
      f4 acc[16];
      #pragma unroll
      for (int j = 0; j < 16; ++j) acc[j] = *(const f4*)(b1 + cb + 4 * j);
      #pragma unroll 4
      for (int k4 = 0; k4 < 32; ++k4) {
        f4 xk = *(const f4*)&xb[(k4 ^ (n & 7)) * 4];
        #pragma unroll
        for (int kk = 0; kk < 4; ++kk) {
          const float* wr = W1 + (4 * k4 + kk) * HN + cb;   // wave-uniform -> SMEM
          #pragma unroll
          for (int j = 0; j < 16; ++j) {
            f4 w = *(const f4*)(wr + 4 * j);
            acc[j] += w * xk[kk];
          }
        }
      }
      #pragma unroll
      for (int j = 0; j < 16; ++j) {
        #pragma unroll
        for (int m = 0; m < 4; ++m) {
          float h = tanh_fast(acc[j][m]);
          f2 w2v = *(const f2*)(W2 + (cb + 4 * j + m) * 2);  // wave-uniform
          zp[0] = fmaf(h, w2v[0], zp[0]);
          zp[1] = fmaf(h, w2v[1], zp[1]);
        }
      }
      zx[tm][role][l] = zp;
    }
    __syncthreads();   // B2: z partials ready

    // ---- softmax + gumbel (both waves compute; role 0 writes) ----
    float vSLN, vSLN2, vL2p, vpres;
    {
      f2 zo = zx[tm][role ^ 1][l];
      float za = zp[0] + zo[0] + b20, zb = zp[1] + zo[1] + b21;
      float zm = fmaxf(za, zb);
      float e0 = __expf(za - zm), e1 = __expf(zb - zm);
      float a0 = e0 / (e0 + e1);
      f2 gnr = *(const f2*)(gn + (nb + n) * 2);
      float q0 = a0 + gnr[0], q1 = (1.f - a0) + gnr[1];
      float qm = fmaxf(q0, q1);
      float E0 = __expf(q0 - qm), E1 = __expf(q1 - qm);
      float lp = E0 / (E0 + E1), ln = 1.f - lp;
      if (role == 0) {
        lp_s[tm][gh][n] = lp;
        a0_s[tm][gh][n] = a0;
        out[2 * GL + nb + n] = (lp > 0.5f) ? 1.0f : 0.0f;   // active
      }
      vSLN = ln; vSLN2 = ln * ln; vL2p = lp * lp;
      vpres = (a0 > 0.5f) ? 1.f : 0.f;
      #pragma unroll
      for (int m = 1; m <= 16; m <<= 1) {   // half-wave (per-graph) reduce
        vSLN  += __shfl_xor(vSLN,  m, 64);
        vSLN2 += __shfl_xor(vSLN2, m, 64);
        vL2p  += __shfl_xor(vL2p,  m, 64);
        vpres += __shfl_xor(vpres, m, 64);
      }
    }
    __syncthreads();   // B3: lp/a0 ready

    // ---- fused moments pass: lane owns features {cb+2n, cb+2n+1} of graph gh ----
    {
      const float* tb = &xt[tm * 2 + gh][0];
      const float* ug = un + nb * HN + cb + 2 * n;
      const int cch  = role * 16 + (n >> 1);   // logical chunk of feature pair
      const int eoff = (2 * n) & 3;            // element offset within chunk
      f2 S1={0,0}, S2={0,0}, A={0,0}, Q1={0,0}, Q2={0,0}, B={0,0};
      #pragma unroll 4
      for (int nd = 0; nd < NPG; ++nd) {
        f2 xv = *(const f2*)&tb[nd * SX + (cch ^ (nd & 7)) * 4 + eoff];
        f2 uv = *(const f2*)(ug + nd * HN);
        float lpn = lp_s[tm][gh][nd];
        float lnn = 1.f - lpn, lq = lpn * lpn;
        f2 tq = xv * xv;
        S1 += xv; S2 += tq;
        A[0]  = fmaf(lpn, xv[0], A[0]);  A[1]  = fmaf(lpn, xv[1], A[1]);
        Q1[0] = fmaf(lq,  xv[0], Q1[0]); Q1[1] = fmaf(lq,  xv[1], Q1[1]);
        Q2[0] = fmaf(lq,  tq[0], Q2[0]); Q2[1] = fmaf(lq,  tq[1], Q2[1]);
        B[0]  = fmaf(lnn, uv[0], B[0]);  B[1]  = fmaf(lnn, uv[1], B[1]);
      }
      // finalize this feature pair
      float m0 = S1[0] * (1.f / NPG), m1 = S1[1] * (1.f / NPG);
      float v0 = fmaxf((S2[0] - S1[0] * m0) * (1.f / (NPG - 1)), 0.f);
      float v1 = fmaxf((S2[1] - S1[1] * m1) * (1.f / (NPG - 1)), 0.f);
      float sd0 = sqrtf(v0), sd1 = sqrtf(v1);
      float in0 = 1.f / (sd0 + 1e-7f), in1 = 1.f / (sd1 + 1e-7f);
      float iv0 = in0 * in0, iv1 = in1 * in1;
      const long fo = g * HN + cb + 2 * n;
      *(f2*)&out[fo] = S1;                                   // graph_emb
      f2 ne;
      ne[0] = fmaf(m0, vSLN, A[0]) + sd0 * B[0];
      ne[1] = fmaf(m1, vSLN, A[1]) + sd1 * B[1];
      *(f2*)&out[GL + fo] = ne;                              // noisy_emb
      float tv = iv0 * (Q2[0] - 2.f * m0 * Q1[0] + m0 * m0 * vL2p)
               + iv1 * (Q2[1] - 2.f * m1 * Q1[1] + m1 * m1 * vL2p);
      float r0 = sd0 * in0, r1 = sd1 * in1;
      float rr = r0 * r0 + r1 * r1;
      #pragma unroll
      for (int m = 1; m <= 16; m <<= 1) {
        tv += __shfl_xor(tv, m, 64);
        rr += __shfl_xor(rr, m, 64);
      }
      if (n == 0) { part[tm][role][gh][0] = tv; part[tm][role][gh][1] = rr; }
    }
    __syncthreads();   // B4: partials ready, tile free

    // ---- edges + per-graph scalars (role-0 wave only) ----
    if (role == 0) {
      float c00 = 0.f, c01 = 0.f, c10 = 0.f, c11 = 0.f;
      for (int e = n; e < epg; e += NPG) {
        int s2 = ei[g * epg + e] - (int)nb;
        int d2 = ei[E + g * epg + e] - (int)nb;
        float as0 = a0_s[tm][gh][s2], as1 = 1.f - as0;
        float ad0 = a0_s[tm][gh][d2], ad1 = 1.f - ad0;
        c00 = fmaf(as0, ad0, c00); c01 = fmaf(as0, ad1, c01);
        c10 = fmaf(as1, ad0, c10); c11 = fmaf(as1, ad1, c11);
      }
      #pragma unroll
      for (int m = 1; m <= 16; m <<= 1) {
        c00 += __shfl_xor(c00, m, 64); c01 += __shfl_xor(c01, m, 64);
        c10 += __shfl_xor(c10, m, 64); c11 += __shfl_xor(c11, m, 64);
      }
      if (n == 0) {
        float tv = part[tm][0][gh][0] + part[tm][1][gh][0];
        float rr = part[tm][0][gh][1] + part[tm][1][gh][1];
        float d0 = c00 / fmaxf(fabsf(c00) + fabsf(c01), 1e-12f);
        float d1 = c11 / fmaxf(fabsf(c10) + fabsf(c11), 1e-12f);
        float pen = 0.5f * ((d0 - 1.f) * (d0 - 1.f) + (d1 - 1.f) * (d1 - 1.f));
        float kl  = (0.5f * vSLN2 * rr + (float)NPG * tv) / (float)(NPG * HN);
        ws[g]                 = kl;
        ws[(size_t)G + g]     = pen;
        ws[2 * (size_t)G + g] = vpres * (1.0f / NPG);
      }
    }
  }
}

// deterministic fixed-order reduction of the 3 per-graph scalar arrays
__global__ __launch_bounds__(1024) void gib_final(const float* __restrict__ ws,
                                                  float* __restrict__ out,
                                                  int G, long base)
{
  __shared__ float red[3][16];
  const int t = threadIdx.x, w = t >> 6, lid = t & 63;
  float s0 = 0.f, s1 = 0.f, s2 = 0.f;
  for (int i = t; i < G; i += 1024) {
    s0 += ws[(size_t)G + i];       // pos_penalty
    s1 += ws[i];                   // kl
    s2 += ws[2 * (size_t)G + i];   // preserve
  }
  #pragma unroll
  for (int m = 1; m <= 32; m <<= 1) {
    s0 += __shfl_xor(s0, m, 64);
    s1 += __shfl_xor(s1, m, 64);
    s2 += __shfl_xor(s2, m, 64);
  }
  if (lid == 0) { red[0][w] = s0; red[1][w] = s1; red[2][w] = s2; }
  __syncthreads();
  if (t == 0) {
    float r0 = 0.f, r1 = 0.f, r2 = 0.f;
    for (int i = 0; i < 16; ++i) { r0 += red[0][i]; r1 += red[1][i]; r2 += red[2][i]; }
    out[base + 0] = r0 / (float)G;
    out[base + 1] = r1 / (float)G;
    out[base + 2] = r2 / (float)G;
  }
}

extern "C" void kernel_launch(void* const* d_in, const int* in_sizes, int n_in,
                              void* d_out, int out_size, void* d_ws, size_t ws_size,
                              hipStream_t stream)
{
  const float* x  = (const float*)d_in[0];
  const float* W1 = (const float*)d_in[1];
  const float* b1 = (const float*)d_in[2];
  const float* W2 = (const float*)d_in[3];
  const float* b2 = (const float*)d_in[4];
  const float* gn = (const float*)d_in[5];
  const float* un = (const float*)d_in[6];
  const int*   ei = (const int*)d_in[7];
  float* out = (float*)d_out;
  float* ws  = (float*)d_ws;

  const long N = (long)in_sizes[0] / HN;
  const int  G = (int)(N / NPG);
  const long E = (long)in_sizes[7] / 2;
  const int epg = (int)(E / G);

  const long graphsPerBlock = 2L * NTEAM * SPS;   // 128
  const int nblocks = (int)((G + graphsPerBlock - 1) / graphsPerBlock);   // 256
  hipLaunchKernelGGL(gib_main, dim3(nblocks), dim3(NT), 0, stream,
                     x, W1, b1, W2, b2, gn, un, ei, out, ws, G, E, epg);
  const long base = 2L * (long)G * HN + N;
  hipLaunchKernelGGL(gib_final, dim3(1), dim3(1024), 0, stream, ws, out, G, base);
}

// Round 15
// 2107.691 us; speedup vs baseline: 1.1945x; 1.1945x over previous
//
#include <hip/hip_runtime.h>

#define HN   128
#define NPG  32
#define NT   512
#define NWAV 8     // waves per block; each wave owns 2 graphs (lane = node)
#define SPP  4     // graph-pairs per wave (serial)

typedef float f4 __attribute__((ext_vector_type(4)));
typedef float f2 __attribute__((ext_vector_type(2)));

__device__ __forceinline__ float tanh_fast(float v) {
  // tanh(v) = 1 - 2/(1+exp(2v)); saturates gracefully at +-1
  return 1.0f - 2.0f / (1.0f + __expf(2.0f * v));
}

__global__ __launch_bounds__(NT, 2) void gib_main(
    const float* __restrict__ x,  const float* __restrict__ W1,
    const float* __restrict__ b1, const float* __restrict__ W2,
    const float* __restrict__ b2, const float* __restrict__ gn,
    const float* __restrict__ un, const int* __restrict__ ei,
    float* __restrict__ out, float* __restrict__ ws,
    int G, long E, int epg)
{
  const int t  = threadIdx.x;
  const int wv = t >> 6;    // wave 0..7
  const int l  = t & 63;
  const int gh = l >> 5;    // graph within pair
  const int n  = l & 31;    // this lane's node

  __shared__ float s_lp[NWAV][2][NPG];
  __shared__ float s_a0[NWAV][2][NPG];

  const long GL  = (long)G * HN;
  const float b20 = b2[0], b21 = b2[1];

  const long pr0 = ((long)blockIdx.x * NWAV + wv) * SPP;

  for (int si = 0; si < SPP; ++si) {
    const long pr = pr0 + si;
    if (2 * pr >= G) break;              // wave-uniform exit
    const long g = 2 * pr + gh;
    if (g < G) {
      const long nb = g * NPG;
      const float* xrow = x + (nb + n) * HN;   // lane's node row
      const float* xgg  = x + nb * HN;
      const float* ug   = un + nb * HN;

      // ---- load lane's full x row into registers (x read ONCE for the MLP) ----
      f4 row[32];
      #pragma unroll
      for (int r = 0; r < 32; ++r) row[r] = *(const f4*)(xrow + 4 * r);

      // ================= MLP: 4 passes of 32 cols, operands reg/SGPR ==========
      float z0 = 0.f, z1 = 0.f;
      #pragma unroll
      for (int p = 0; p < 4; ++p) {
        const int c0 = p * 32;
        const float* w2p = W2 + c0 * 2;
        f4 acc[8];
        #pragma unroll
        for (int j = 0; j < 8; ++j) {          // b1: wave-uniform loads
          const float* bp = b1 + c0 + 4 * j;
          acc[j][0] = bp[0]; acc[j][1] = bp[1];
          acc[j][2] = bp[2]; acc[j][3] = bp[3];
        }
        #pragma unroll
        for (int k4 = 0; k4 < 32; ++k4) {
          #pragma unroll
          for (int kk = 0; kk < 4; ++kk) {
            const float* wr = W1 + (4 * k4 + kk) * HN + c0;  // wave-uniform (SMEM)
            const float xk = row[k4][kk];
            #pragma unroll
            for (int j = 0; j < 8; ++j) {
              acc[j][0] = fmaf(wr[4*j+0], xk, acc[j][0]);
              acc[j][1] = fmaf(wr[4*j+1], xk, acc[j][1]);
              acc[j][2] = fmaf(wr[4*j+2], xk, acc[j][2]);
              acc[j][3] = fmaf(wr[4*j+3], xk, acc[j][3]);
            }
          }
        }
        #pragma unroll
        for (int j = 0; j < 8; ++j) {
          #pragma unroll
          for (int m = 0; m < 4; ++m) {
            float h = tanh_fast(acc[j][m]);
            z0 = fmaf(h, w2p[(4*j+m)*2 + 0], z0);
            z1 = fmaf(h, w2p[(4*j+m)*2 + 1], z1);
          }
        }
      }

      // ================= softmax + gumbel (lane = its node) ==================
      float vSLN, vSLN2, vL2p, vpres;
      {
        float za = z0 + b20, zb = z1 + b21;
        float zm = fmaxf(za, zb);
        float e0 = __expf(za - zm), e1 = __expf(zb - zm);
        float a0 = e0 / (e0 + e1);
        f2 gnr = *(const f2*)(gn + (nb + n) * 2);
        float q0 = a0 + gnr[0], q1 = (1.f - a0) + gnr[1];
        float qm = fmaxf(q0, q1);
        float E0 = __expf(q0 - qm), E1 = __expf(q1 - qm);
        float lp = E0 / (E0 + E1), ln = 1.f - lp;
        s_lp[wv][gh][n] = lp;
        s_a0[wv][gh][n] = a0;
        out[2 * GL + nb + n] = (lp > 0.5f) ? 1.0f : 0.0f;   // active
        vSLN = ln; vSLN2 = ln * ln; vL2p = lp * lp; vpres = (a0 > 0.5f) ? 1.f : 0.f;
        #pragma unroll
        for (int m = 1; m <= 16; m <<= 1) {   // half-wave (per-graph) reduce
          vSLN  += __shfl_xor(vSLN,  m, 64);
          vSLN2 += __shfl_xor(vSLN2, m, 64);
          vL2p  += __shfl_xor(vL2p,  m, 64);
          vpres += __shfl_xor(vpres, m, 64);
        }
      }

      // ========== fused moments pass: S1,S2,A,Q1,Q2,B per feature ============
      // lane owns features {2n,2n+1} (half A) and {64+2n,65+2n} (half B)
      f2 S1a={0,0}, S2a={0,0}, Aa={0,0}, Q1a={0,0}, Q2a={0,0}, Ba={0,0};
      f2 S1b={0,0}, S2b={0,0}, Ab={0,0}, Q1b={0,0}, Q2b={0,0}, Bb={0,0};
      #pragma unroll 4
      for (int nd = 0; nd < NPG; ++nd) {
        f2 xa = *(const f2*)(xgg + nd * HN + 2 * n);
        f2 xb = *(const f2*)(xgg + nd * HN + 64 + 2 * n);
        f2 ua = *(const f2*)(ug  + nd * HN + 2 * n);
        f2 ub = *(const f2*)(ug  + nd * HN + 64 + 2 * n);
        float lpn = s_lp[wv][gh][nd];
        float lnn = 1.f - lpn;
        float lq  = lpn * lpn;
        f2 ta = xa * xa, tb = xb * xb;
        S1a += xa; S1b += xb;
        S2a += ta; S2b += tb;
        Aa[0] = fmaf(lpn, xa[0], Aa[0]); Aa[1] = fmaf(lpn, xa[1], Aa[1]);
        Ab[0] = fmaf(lpn, xb[0], Ab[0]); Ab[1] = fmaf(lpn, xb[1], Ab[1]);
        Q1a[0] = fmaf(lq, xa[0], Q1a[0]); Q1a[1] = fmaf(lq, xa[1], Q1a[1]);
        Q1b[0] = fmaf(lq, xb[0], Q1b[0]); Q1b[1] = fmaf(lq, xb[1], Q1b[1]);
        Q2a[0] = fmaf(lq, ta[0], Q2a[0]); Q2a[1] = fmaf(lq, ta[1], Q2a[1]);
        Q2b[0] = fmaf(lq, tb[0], Q2b[0]); Q2b[1] = fmaf(lq, tb[1], Q2b[1]);
        Ba[0] = fmaf(lnn, ua[0], Ba[0]); Ba[1] = fmaf(lnn, ua[1], Ba[1]);
        Bb[0] = fmaf(lnn, ub[0], Bb[0]); Bb[1] = fmaf(lnn, ub[1], Bb[1]);
      }

      // ---- finalize per-feature stats, graph_emb, noisy_emb, T2, r2 ----
      float tv = 0.f, rr = 0.f;
      {
        f2 ne;
        // half A
        {
          float m0 = S1a[0] * (1.f / NPG), m1 = S1a[1] * (1.f / NPG);
          float v0 = fmaxf((S2a[0] - S1a[0] * m0) * (1.f / (NPG - 1)), 0.f);
          float v1 = fmaxf((S2a[1] - S1a[1] * m1) * (1.f / (NPG - 1)), 0.f);
          float sd0 = sqrtf(v0), sd1 = sqrtf(v1);
          float in0 = 1.f / (sd0 + 1e-7f), in1 = 1.f / (sd1 + 1e-7f);
          float iv0 = in0 * in0, iv1 = in1 * in1;
          ne[0] = fmaf(m0, vSLN, Aa[0]) + sd0 * Ba[0];
          ne[1] = fmaf(m1, vSLN, Aa[1]) + sd1 * Ba[1];
          *(f2*)&out[GL + g * HN + 2 * n] = ne;          // noisy low
          *(f2*)&out[g * HN + 2 * n] = S1a;              // graph_emb low
          tv += iv0 * (Q2a[0] - 2.f * m0 * Q1a[0] + m0 * m0 * vL2p)
              + iv1 * (Q2a[1] - 2.f * m1 * Q1a[1] + m1 * m1 * vL2p);
          float r0 = sd0 * in0, r1 = sd1 * in1;
          rr += r0 * r0 + r1 * r1;
        }
        // half B
        {
          float m0 = S1b[0] * (1.f / NPG), m1 = S1b[1] * (1.f / NPG);
          float v0 = fmaxf((S2b[0] - S1b[0] * m0) * (1.f / (NPG - 1)), 0.f);
          float v1 = fmaxf((S2b[1] - S1b[1] * m1) * (1.f / (NPG - 1)), 0.f);
          float sd0 = sqrtf(v0), sd1 = sqrtf(v1);
          float in0 = 1.f / (sd0 + 1e-7f), in1 = 1.f / (sd1 + 1e-7f);
          float iv0 = in0 * in0, iv1 = in1 * in1;
          ne[0] = fmaf(m0, vSLN, Ab[0]) + sd0 * Bb[0];
          ne[1] = fmaf(m1, vSLN, Ab[1]) + sd1 * Bb[1];
          *(f2*)&out[GL + g * HN + 64 + 2 * n] = ne;     // noisy high
          *(f2*)&out[g * HN + 64 + 2 * n] = S1b;         // graph_emb high
          tv += iv0 * (Q2b[0] - 2.f * m0 * Q1b[0] + m0 * m0 * vL2p)
              + iv1 * (Q2b[1] - 2.f * m1 * Q1b[1] + m1 * m1 * vL2p);
          float r0 = sd0 * in0, r1 = sd1 * in1;
          rr += r0 * r0 + r1 * r1;
        }
        #pragma unroll
        for (int m = 1; m <= 16; m <<= 1) {
          tv += __shfl_xor(tv, m, 64);
          rr += __shfl_xor(rr, m, 64);
        }
      }

      // ================= edges -> 2x2 adjacency; per-graph scalars ===========
      {
        float c00 = 0.f, c01 = 0.f, c10 = 0.f, c11 = 0.f;
        for (int e = n; e < epg; e += NPG) {
          int s2 = ei[g * epg + e] - (int)nb;
          int d2 = ei[E + g * epg + e] - (int)nb;
          float as0 = s_a0[wv][gh][s2], as1 = 1.f - as0;
          float ad0 = s_a0[wv][gh][d2], ad1 = 1.f - ad0;
          c00 = fmaf(as0, ad0, c00); c01 = fmaf(as0, ad1, c01);
          c10 = fmaf(as1, ad0, c10); c11 = fmaf(as1, ad1, c11);
        }
        #pragma unroll
        for (int m = 1; m <= 16; m <<= 1) {
          c00 += __shfl_xor(c00, m, 64); c01 += __shfl_xor(c01, m, 64);
          c10 += __shfl_xor(c10, m, 64); c11 += __shfl_xor(c11, m, 64);
        }
        if (n == 0) {
          float d0 = c00 / fmaxf(fabsf(c00) + fabsf(c01), 1e-12f);
          float d1 = c11 / fmaxf(fabsf(c10) + fabsf(c11), 1e-12f);
          float pen = 0.5f * ((d0 - 1.f) * (d0 - 1.f) + (d1 - 1.f) * (d1 - 1.f));
          float kl = (0.5f * vSLN2 * rr + (float)NPG * tv) / (float)(NPG * HN);
          ws[g]                 = kl;
          ws[(size_t)G + g]     = pen;
          ws[2 * (size_t)G + g] = vpres * (1.0f / NPG);
        }
      }
    }
  }
}

// deterministic fixed-order reduction of the 3 per-graph scalar arrays
__global__ __launch_bounds__(1024) void gib_final(const float* __restrict__ ws,
                                                  float* __restrict__ out,
                                                  int G, long base)
{
  __shared__ float red[3][16];
  const int t = threadIdx.x, w = t >> 6, lid = t & 63;
  float s0 = 0.f, s1 = 0.f, s2 = 0.f;
  for (int i = t; i < G; i += 1024) {
    s0 += ws[(size_t)G + i];       // pos_penalty
    s1 += ws[i];                   // kl
    s2 += ws[2 * (size_t)G + i];   // preserve
  }
  #pragma unroll
  for (int m = 1; m <= 32; m <<= 1) {
    s0 += __shfl_xor(s0, m, 64);
    s1 += __shfl_xor(s1, m, 64);
    s2 += __shfl_xor(s2, m, 64);
  }
  if (lid == 0) { red[0][w] = s0; red[1][w] = s1; red[2][w] = s2; }
  __syncthreads();
  if (t == 0) {
    float r0 = 0.f, r1 = 0.f, r2 = 0.f;
    for (int i = 0; i < 16; ++i) { r0 += red[0][i]; r1 += red[1][i]; r2 += red[2][i]; }
    out[base + 0] = r0 / (float)G;
    out[base + 1] = r1 / (float)G;
    out[base + 2] = r2 / (float)G;
  }
}

extern "C" void kernel_launch(void* const* d_in, const int* in_sizes, int n_in,
                              void* d_out, int out_size, void* d_ws, size_t ws_size,
                              hipStream_t stream)
{
  const float* x  = (const float*)d_in[0];
  const float* W1 = (const float*)d_in[1];
  const float* b1 = (const float*)d_in[2];
  const float* W2 = (const float*)d_in[3];
  const float* b2 = (const float*)d_in[4];
  const float* gn = (const float*)d_in[5];
  const float* un = (const float*)d_in[6];
  const int*   ei = (const int*)d_in[7];
  float* out = (float*)d_out;
  float* ws  = (float*)d_ws;

  const long N = (long)in_sizes[0] / HN;
  const int  G = (int)(N / NPG);
  const long E = (long)in_sizes[7] / 2;
  const int epg = (int)(E / G);

  const long graphsPerBlock = 2L * NWAV * SPP;   // 64
  const int nblocks = (int)((G + graphsPerBlock - 1) / graphsPerBlock);   // 512
  hipLaunchKernelGGL(gib_main, dim3(nblocks), dim3(NT), 0, stream,
                     x, W1, b1, W2, b2, gn, un, ei, out, ws, G, E, epg);
  const long base = 2L * (long)G * HN + N;
  hipLaunchKernelGGL(gib_final, dim3(1), dim3(1024), 0, stream, ws, out, G, base);
}

// Round 16
// 741.125 us; speedup vs baseline: 3.3972x; 2.8439x over previous
//
#include <hip/hip_runtime.h>

#define HN  128
#define NPG 32
#define NT  512
#define NW  8      // waves per block; 1 wave == 1 graph
#define SPW 8      // graphs per wave (serial)
#define HK  64     // half feature width resident in LDS
#define SXH 68     // padded row stride (floats) for half tile

typedef float f4 __attribute__((ext_vector_type(4)));
typedef float f2 __attribute__((ext_vector_type(2)));

__device__ __forceinline__ float tanh_fast(float v) {
  // tanh(v) = 1 - 2/(1+exp(2v)); saturates gracefully at +-1
  return 1.0f - 2.0f / (1.0f + __expf(2.0f * v));
}

__global__ __launch_bounds__(NT, 2) void gib_main(
    const float* __restrict__ x,  const float* __restrict__ W1,
    const float* __restrict__ b1, const float* __restrict__ W2,
    const float* __restrict__ b2, const float* __restrict__ gn,
    const float* __restrict__ un, const int* __restrict__ ei,
    float* __restrict__ out, float* __restrict__ ws,
    int G, long E, int epg)
{
  const int t  = threadIdx.x;
  const int wv = t >> 6;
  const int l  = t & 63;
  const int ng = l & 3;    // node group: nodes ng+4i, i=0..7
  const int cg = l >> 2;   // col group: cols 8cg..8cg+7
  const int sr = l >> 4;   // staging row base (rows sr+4r)
  const int sc = l & 15;   // staging chunk

  __shared__ __align__(16) float xs[NW][NPG * SXH];     // 8 x 8.7 KB half tiles
  __shared__ float s_lp[NW][NPG], s_a0[NW][NPG];

  const long GL = (long)G * HN;

  float* xh = &xs[wv][0];
  const float b20 = b2[0], b21 = b2[1];

  const long gbase = ((long)blockIdx.x * NW + wv) * SPW;

  // ---- prologue: stage h0 (k 0..63) of first graph (wave-local, no barrier) ----
  {
    const float* xg0 = x + gbase * NPG * HN;
    #pragma unroll
    for (int r = 0; r < 8; ++r) {
      int n = sr + 4 * r;
      f4 v = *(const f4*)(xg0 + n * HN + sc * 4);
      *(f4*)&xh[n * SXH + sc * 4] = v;
    }
  }

  for (int si = 0; si < SPW; ++si) {
    const long g = gbase + si;
    if (g >= G) break;
    const long nb = g * NPG;
    const float* xg = x + nb * HN;
    const float* ug = un + nb * HN;

    // ================= MLP phase 0 (k 0..63), 8 nodes x 8 cols =================
    f4 accA[8], accB[8];
    {
      f4 b1A = *(const f4*)(b1 + 8 * cg);
      f4 b1B = *(const f4*)(b1 + 8 * cg + 4);
      #pragma unroll
      for (int i = 0; i < 8; ++i) { accA[i] = b1A; accB[i] = b1B; }
    }
    #pragma unroll 4
    for (int kc = 0; kc < 16; ++kc) {
      f4 wA[4], wB[4];
      #pragma unroll
      for (int kk = 0; kk < 4; ++kk) {
        wA[kk] = *(const f4*)(W1 + (kc * 4 + kk) * HN + 8 * cg);      // L2-hot
        wB[kk] = *(const f4*)(W1 + (kc * 4 + kk) * HN + 8 * cg + 4);
      }
      #pragma unroll
      for (int i = 0; i < 8; ++i) {
        f4 xv = *(const f4*)&xh[(ng + 4 * i) * SXH + kc * 4];
        #pragma unroll
        for (int kk = 0; kk < 4; ++kk) {
          accA[i] += wA[kk] * xv[kk];
          accB[i] += wB[kk] * xv[kk];
        }
      }
    }

    // ---- h1 prefetch: issued only AFTER phase 0 (keeps peak liveness < 128) ----
    __builtin_amdgcn_sched_barrier(0);
    f4 h1b[8];
    #pragma unroll
    for (int r = 0; r < 8; ++r)
      h1b[r] = *(const f4*)(xg + (sr + 4 * r) * HN + HK + sc * 4);
    __builtin_amdgcn_sched_barrier(0);

    // ---- stats pass (global x, L2-hot) — covers h1b latency ----
    f2 mu, sd, iv;
    float r2acc;
    {
      float s10 = 0.f, s11 = 0.f, s20 = 0.f, s21 = 0.f;
      #pragma unroll
      for (int n = 0; n < NPG; ++n) {
        f2 v = *(const f2*)(xg + n * HN + 2 * l);
        s10 += v[0]; s11 += v[1];
        s20 = fmaf(v[0], v[0], s20);
        s21 = fmaf(v[1], v[1], s21);
      }
      float m0 = s10 * (1.f / NPG), m1 = s11 * (1.f / NPG);
      float v0 = fmaxf((s20 - s10 * m0) * (1.f / (NPG - 1)), 0.f);
      float v1 = fmaxf((s21 - s11 * m1) * (1.f / (NPG - 1)), 0.f);
      float sd0 = sqrtf(v0), sd1 = sqrtf(v1);
      float in0 = 1.f / (sd0 + 1e-7f), in1 = 1.f / (sd1 + 1e-7f);
      mu[0] = m0; mu[1] = m1; sd[0] = sd0; sd[1] = sd1;
      iv[0] = in0 * in0; iv[1] = in1 * in1;
      f2 ge; ge[0] = s10; ge[1] = s11;
      *(f2*)&out[g * HN + 2 * l] = ge;              // graph_emb
      float r0 = sd0 * in0, r1 = sd1 * in1;
      float rr = r0 * r0 + r1 * r1;
      #pragma unroll
      for (int m = 1; m <= 32; m <<= 1) rr += __shfl_xor(rr, m, 64);
      r2acc = rr;
    }

    // ---- overwrite tile with h1 ----
    #pragma unroll
    for (int r = 0; r < 8; ++r)
      *(f4*)&xh[(sr + 4 * r) * SXH + sc * 4] = h1b[r];

    // ================= MLP phase 1 (k 64..127) =================
    #pragma unroll 4
    for (int kc = 0; kc < 16; ++kc) {
      f4 wA[4], wB[4];
      #pragma unroll
      for (int kk = 0; kk < 4; ++kk) {
        wA[kk] = *(const f4*)(W1 + (HK + kc * 4 + kk) * HN + 8 * cg);
        wB[kk] = *(const f4*)(W1 + (HK + kc * 4 + kk) * HN + 8 * cg + 4);
      }
      #pragma unroll
      for (int i = 0; i < 8; ++i) {
        f4 xv = *(const f4*)&xh[(ng + 4 * i) * SXH + kc * 4];
        #pragma unroll
        for (int kk = 0; kk < 4; ++kk) {
          accA[i] += wA[kk] * xv[kk];
          accB[i] += wB[kk] * xv[kk];
        }
      }
    }

    // ---- epilogue: tanh -> W2 (loaded here; disjoint live range) ----
    float z0[8], z1[8];
    {
      f4 w2a = *(const f4*)(W2 + 16 * cg);
      f4 w2b = *(const f4*)(W2 + 16 * cg + 4);
      f4 w2c = *(const f4*)(W2 + 16 * cg + 8);
      f4 w2d = *(const f4*)(W2 + 16 * cg + 12);
      #pragma unroll
      for (int i = 0; i < 8; ++i) {
        float h0 = tanh_fast(accA[i][0]), h1 = tanh_fast(accA[i][1]);
        float h2 = tanh_fast(accA[i][2]), h3 = tanh_fast(accA[i][3]);
        float h4 = tanh_fast(accB[i][0]), h5 = tanh_fast(accB[i][1]);
        float h6 = tanh_fast(accB[i][2]), h7 = tanh_fast(accB[i][3]);
        float a = h0*w2a[0] + h1*w2a[2] + h2*w2b[0] + h3*w2b[2]
                + h4*w2c[0] + h5*w2c[2] + h6*w2d[0] + h7*w2d[2];
        float b = h0*w2a[1] + h1*w2a[3] + h2*w2b[1] + h3*w2b[3]
                + h4*w2c[1] + h5*w2c[3] + h6*w2d[1] + h7*w2d[3];
        #pragma unroll
        for (int m = 4; m <= 32; m <<= 1) {
          a += __shfl_xor(a, m, 64);
          b += __shfl_xor(b, m, 64);
        }
        z0[i] = a; z1[i] = b;
      }
    }

    // ---- next graph's h0 prefetch (fenced both sides) ----
    __builtin_amdgcn_sched_barrier(0);
    f4 h0b[8];
    const bool more = (si + 1 < SPW) && (g + 1 < G);
    if (more) {
      const float* xn = x + (g + 1) * NPG * HN;
      #pragma unroll
      for (int r = 0; r < 8; ++r)
        h0b[r] = *(const f4*)(xn + (sr + 4 * r) * HN + sc * 4);
    }
    __builtin_amdgcn_sched_barrier(0);

    // ---- softmax + gumbel (replicated across cg; cg==0 writes) ----
    float vSLN = 0.f, vSLN2 = 0.f, vpres = 0.f;
    #pragma unroll
    for (int i = 0; i < 8; ++i) {
      const int n = ng + 4 * i;
      f2 gnr = *(const f2*)(gn + (nb + n) * 2);
      float za = z0[i] + b20, zb = z1[i] + b21;
      float zm = fmaxf(za, zb);
      float e0 = __expf(za - zm), e1 = __expf(zb - zm);
      float a0 = e0 / (e0 + e1), a1 = 1.f - a0;
      float q0 = a0 + gnr[0], q1 = a1 + gnr[1];
      float qm = fmaxf(q0, q1);
      float E0 = __expf(q0 - qm), E1 = __expf(q1 - qm);
      float lp = E0 / (E0 + E1), ln = 1.f - lp;
      if (cg == 0) { s_lp[wv][n] = lp; s_a0[wv][n] = a0; }
      vSLN += ln; vSLN2 += ln * ln; vpres += (a0 > 0.5f) ? 1.f : 0.f;
    }
    vSLN  += __shfl_xor(vSLN, 1, 64);  vSLN  += __shfl_xor(vSLN, 2, 64);
    vSLN2 += __shfl_xor(vSLN2, 1, 64); vSLN2 += __shfl_xor(vSLN2, 2, 64);
    vpres += __shfl_xor(vpres, 1, 64); vpres += __shfl_xor(vpres, 2, 64);

    if (l < NPG)
      out[2 * GL + nb + l] = (s_lp[wv][l] > 0.5f) ? 1.0f : 0.0f;   // active

    // ---- T2 + noisy_emb (x, un from global) ----
    float tv = 0.f, A0 = 0.f, A1 = 0.f, B0 = 0.f, B1 = 0.f;
    #pragma unroll 8
    for (int n = 0; n < NPG; ++n) {
      f2 xv = *(const f2*)(xg + n * HN + 2 * l);
      f2 uv = *(const f2*)(ug + n * HN + 2 * l);
      float lpn = s_lp[wv][n];
      float lnn = 1.f - lpn;
      float d0 = xv[0] - mu[0], d1 = xv[1] - mu[1];
      tv = fmaf(lpn * lpn, fmaf(d0 * d0, iv[0], d1 * d1 * iv[1]), tv);
      A0 = fmaf(lpn, xv[0], A0); A1 = fmaf(lpn, xv[1], A1);
      B0 = fmaf(lnn, uv[0], B0); B1 = fmaf(lnn, uv[1], B1);
    }
    {
      f2 ne;
      ne[0] = fmaf(mu[0], vSLN, A0) + sd[0] * B0;
      ne[1] = fmaf(mu[1], vSLN, A1) + sd[1] * B1;
      *(f2*)&out[GL + g * HN + 2 * l] = ne;        // noisy_emb
    }
    #pragma unroll
    for (int m = 1; m <= 32; m <<= 1) tv += __shfl_xor(tv, m, 64);

    // ---- edges -> 2x2 adjacency ----
    float c00 = 0.f, c01 = 0.f, c10 = 0.f, c11 = 0.f;
    for (int e = l; e < epg; e += 64) {
      int s2 = ei[g * epg + e] - (int)nb;
      int d2 = ei[E + g * epg + e] - (int)nb;
      float as0 = s_a0[wv][s2], as1 = 1.f - as0;
      float ad0 = s_a0[wv][d2], ad1 = 1.f - ad0;
      c00 = fmaf(as0, ad0, c00); c01 = fmaf(as0, ad1, c01);
      c10 = fmaf(as1, ad0, c10); c11 = fmaf(as1, ad1, c11);
    }
    #pragma unroll
    for (int m = 1; m <= 32; m <<= 1) {
      c00 += __shfl_xor(c00, m, 64); c01 += __shfl_xor(c01, m, 64);
      c10 += __shfl_xor(c10, m, 64); c11 += __shfl_xor(c11, m, 64);
    }
    if (l == 0) {
      float d0 = c00 / fmaxf(fabsf(c00) + fabsf(c01), 1e-12f);
      float d1 = c11 / fmaxf(fabsf(c10) + fabsf(c11), 1e-12f);
      float pen = 0.5f * ((d0 - 1.f) * (d0 - 1.f) + (d1 - 1.f) * (d1 - 1.f));
      float kl = (0.5f * vSLN2 * r2acc + (float)NPG * tv) / (float)(NPG * HN);
      ws[g]                 = kl;
      ws[(size_t)G + g]     = pen;
      ws[2 * (size_t)G + g] = vpres * (1.0f / NPG);
    }

    // ---- stage next graph's h0 ----
    if (more) {
      #pragma unroll
      for (int r = 0; r < 8; ++r)
        *(f4*)&xh[(sr + 4 * r) * SXH + sc * 4] = h0b[r];
    }
  }
}

// deterministic fixed-order reduction of the 3 per-graph scalar arrays
__global__ __launch_bounds__(1024) void gib_final(const float* __restrict__ ws,
                                                  float* __restrict__ out,
                                                  int G, long base)
{
  __shared__ float red[3][16];
  const int t = threadIdx.x, w = t >> 6, lid = t & 63;
  float s0 = 0.f, s1 = 0.f, s2 = 0.f;
  for (int i = t; i < G; i += 1024) {
    s0 += ws[(size_t)G + i];       // pos_penalty
    s1 += ws[i];                   // kl
    s2 += ws[2 * (size_t)G + i];   // preserve
  }
  #pragma unroll
  for (int m = 1; m <= 32; m <<= 1) {
    s0 += __shfl_xor(s0, m, 64);
    s1 += __shfl_xor(s1, m, 64);
    s2 += __shfl_xor(s2, m, 64);
  }
  if (lid == 0) { red[0][w] = s0; red[1][w] = s1; red[2][w] = s2; }
  __syncthreads();
  if (t == 0) {
    float r0 = 0.f, r1 = 0.f, r2 = 0.f;
    for (int i = 0; i < 16; ++i) { r0 += red[0][i]; r1 += red[1][i]; r2 += red[2][i]; }
    out[base + 0] = r0 / (float)G;
    out[base + 1] = r1 / (float)G;
    out[base + 2] = r2 / (float)G;
  }
}

extern "C" void kernel_launch(void* const* d_in, const int* in_sizes, int n_in,
                              void* d_out, int out_size, void* d_ws, size_t ws_size,
                              hipStream_t stream)
{
  const float* x  = (const float*)d_in[0];
  const float* W1 = (const float*)d_in[1];
  const float* b1 = (const float*)d_in[2];
  const float* W2 = (const float*)d_in[3];
  const float* b2 = (const float*)d_in[4];
  const float* gn = (const float*)d_in[5];
  const float* un = (const float*)d_in[6];
  const int*   ei = (const int*)d_in[7];
  float* out = (float*)d_out;
  float* ws  = (float*)d_ws;

  const long N = (long)in_sizes[0] / HN;
  const int  G = (int)(N / NPG);
  const long E = (long)in_sizes[7] / 2;
  const int epg = (int)(E / G);

  const int nblocks = (G + NW * SPW - 1) / (NW * SPW);   // 32768/64 = 512 -> 2 blocks/CU
  hipLaunchKernelGGL(gib_main, dim3(nblocks), dim3(NT), 0, stream,
                     x, W1, b1, W2, b2, gn, un, ei, out, ws, G, E, epg);
  const long base = 2L * (long)G * HN + N;
  hipLaunchKernelGGL(gib_final, dim3(1), dim3(1024), 0, stream, ws, out, G, base);
}

// Round 17
// 654.538 us; speedup vs baseline: 3.8466x; 1.1323x over previous
//
#include <hip/hip_runtime.h>

#define HN  128
#define NPG 32
#define NT  512
#define NW  8      // waves per block; 1 wave == 1 graph
#define SPW 8      // graphs per wave (serial)
#define HK  64     // half feature width resident in LDS
#define SXH 68     // padded row stride (floats) for half tile

typedef float f4 __attribute__((ext_vector_type(4)));
typedef float f2 __attribute__((ext_vector_type(2)));

__device__ __forceinline__ float tanh_fast(float v) {
  return 1.0f - 2.0f / (1.0f + __expf(2.0f * v));
}
// packed-math helpers: lower to v_pk_fma_f32 / v_pk_add_f32 (bit-identical fp32)
__device__ __forceinline__ f4 fma4s(f4 a, float s, f4 c) {
  f4 b = {s, s, s, s};
  return a * b + c;                      // contracts to <4 x float> fma -> 2x v_pk_fma_f32
}
__device__ __forceinline__ f2 fma2s(f2 a, float s, f2 c) {
  f2 b = {s, s};
  return a * b + c;                      // v_pk_fma_f32
}
__device__ __forceinline__ f2 lo2(f4 v) { f2 r = {v[0], v[1]}; return r; }
__device__ __forceinline__ f2 hi2(f4 v) { f2 r = {v[2], v[3]}; return r; }

__global__ __launch_bounds__(NT, 2) void gib_main(
    const float* __restrict__ x,  const float* __restrict__ W1,
    const float* __restrict__ b1, const float* __restrict__ W2,
    const float* __restrict__ b2, const float* __restrict__ gn,
    const float* __restrict__ un, const int* __restrict__ ei,
    float* __restrict__ out, float* __restrict__ ws,
    int G, long E, int epg)
{
  const int t  = threadIdx.x;
  const int wv = t >> 6;
  const int l  = t & 63;
  const int ng = l & 3;    // node group: nodes ng+4i, i=0..7
  const int cg = l >> 2;   // col group: cols 8cg..8cg+7
  const int sr = l >> 4;   // staging row base (rows sr+4r)
  const int sc = l & 15;   // staging chunk

  __shared__ __align__(16) float W1s[HN * HN];          // 64 KB, slot-deinterleaved
  __shared__ __align__(16) float xs[NW][NPG * SXH];     // 8 x 8.7 KB half tiles
  __shared__ float s_lp[NW][NPG], s_a0[NW][NPG];

  const long GL = (long)G * HN;

  // ---- stage W1 once, column-chunk de-interleaved (r10-verified layout) ----
  #pragma unroll
  for (int r = 0; r < 8; ++r) {
    int s = r * NT + t;
    int k = s >> 5, gm = s & 31;
    int slot = ((gm & 1) << 4) | (gm >> 1);
    *(f4*)&W1s[k * HN + slot * 4] = *(const f4*)(W1 + s * 4);
  }
  __syncthreads();   // only block-wide barrier

  float* xh = &xs[wv][0];
  const float b20 = b2[0], b21 = b2[1];

  const long gbase = ((long)blockIdx.x * NW + wv) * SPW;

  // ---- prologue: stage h0 (k 0..63) of first graph ----
  {
    const float* xg0 = x + gbase * NPG * HN;
    #pragma unroll
    for (int r = 0; r < 8; ++r) {
      int n = sr + 4 * r;
      f4 v = *(const f4*)(xg0 + n * HN + sc * 4);
      *(f4*)&xh[n * SXH + sc * 4] = v;
    }
  }

  for (int si = 0; si < SPW; ++si) {
    const long g = gbase + si;
    if (g >= G) break;
    const long nb = g * NPG;
    const float* xg = x + nb * HN;
    const float* ug = un + nb * HN;

    // ================= MLP phase 0 (k 0..63), 8 nodes x 8 cols =================
    f4 accA[8], accB[8];
    {
      f4 b1A = *(const f4*)(b1 + 8 * cg);
      f4 b1B = *(const f4*)(b1 + 8 * cg + 4);
      #pragma unroll
      for (int i = 0; i < 8; ++i) { accA[i] = b1A; accB[i] = b1B; }
    }
    #pragma unroll 4
    for (int kc = 0; kc < 16; ++kc) {
      f4 wA[4], wB[4];
      #pragma unroll
      for (int kk = 0; kk < 4; ++kk) {
        wA[kk] = *(const f4*)&W1s[(kc * 4 + kk) * HN + cg * 4];
        wB[kk] = *(const f4*)&W1s[(kc * 4 + kk) * HN + 64 + cg * 4];
      }
      #pragma unroll
      for (int i = 0; i < 8; ++i) {
        f4 xv = *(const f4*)&xh[(ng + 4 * i) * SXH + kc * 4];
        #pragma unroll
        for (int kk = 0; kk < 4; ++kk) {
          accA[i] = fma4s(wA[kk], xv[kk], accA[i]);
          accB[i] = fma4s(wB[kk], xv[kk], accB[i]);
        }
      }
    }

    // ---- h1 prefetch: issued only AFTER phase 0 (keeps peak liveness < 128) ----
    __builtin_amdgcn_sched_barrier(0);
    f4 h1b[8];
    #pragma unroll
    for (int r = 0; r < 8; ++r)
      h1b[r] = *(const f4*)(xg + (sr + 4 * r) * HN + HK + sc * 4);
    __builtin_amdgcn_sched_barrier(0);

    // ---- stats pass (global x, L2-hot) — covers h1b latency ----
    f2 mu, sd, iv;
    float r2acc;
    {
      f2 s1 = {0.f, 0.f}, s2 = {0.f, 0.f};
      #pragma unroll
      for (int n = 0; n < NPG; ++n) {
        f2 v = *(const f2*)(xg + n * HN + 2 * l);
        s1 += v;                 // v_pk_add_f32
        s2 = v * v + s2;         // v_pk_fma_f32
      }
      float m0 = s1[0] * (1.f / NPG), m1 = s1[1] * (1.f / NPG);
      float v0 = fmaxf((s2[0] - s1[0] * m0) * (1.f / (NPG - 1)), 0.f);
      float v1 = fmaxf((s2[1] - s1[1] * m1) * (1.f / (NPG - 1)), 0.f);
      float sd0 = sqrtf(v0), sd1 = sqrtf(v1);
      float in0 = 1.f / (sd0 + 1e-7f), in1 = 1.f / (sd1 + 1e-7f);
      mu[0] = m0; mu[1] = m1; sd[0] = sd0; sd[1] = sd1;
      iv[0] = in0 * in0; iv[1] = in1 * in1;
      *(f2*)&out[g * HN + 2 * l] = s1;              // graph_emb
      float r0 = sd0 * in0, r1 = sd1 * in1;
      float rr = r0 * r0 + r1 * r1;
      #pragma unroll
      for (int m = 1; m <= 32; m <<= 1) rr += __shfl_xor(rr, m, 64);
      r2acc = rr;
    }

    // ---- overwrite tile with h1 ----
    #pragma unroll
    for (int r = 0; r < 8; ++r)
      *(f4*)&xh[(sr + 4 * r) * SXH + sc * 4] = h1b[r];

    // ================= MLP phase 1 (k 64..127) =================
    #pragma unroll 4
    for (int kc = 0; kc < 16; ++kc) {
      f4 wA[4], wB[4];
      #pragma unroll
      for (int kk = 0; kk < 4; ++kk) {
        wA[kk] = *(const f4*)&W1s[(HK + kc * 4 + kk) * HN + cg * 4];
        wB[kk] = *(const f4*)&W1s[(HK + kc * 4 + kk) * HN + 64 + cg * 4];
      }
      #pragma unroll
      for (int i = 0; i < 8; ++i) {
        f4 xv = *(const f4*)&xh[(ng + 4 * i) * SXH + kc * 4];
        #pragma unroll
        for (int kk = 0; kk < 4; ++kk) {
          accA[i] = fma4s(wA[kk], xv[kk], accA[i]);
          accB[i] = fma4s(wB[kk], xv[kk], accB[i]);
        }
      }
    }

    // ---- epilogue: tanh -> W2 (z packed as f2 = {z0,z1}) ----
    float z0[8], z1[8];
    {
      f4 w2a = *(const f4*)(W2 + 16 * cg);        // rows 8cg,8cg+1 pairs
      f4 w2b = *(const f4*)(W2 + 16 * cg + 4);
      f4 w2c = *(const f4*)(W2 + 16 * cg + 8);
      f4 w2d = *(const f4*)(W2 + 16 * cg + 12);
      #pragma unroll
      for (int i = 0; i < 8; ++i) {
        f2 z = {0.f, 0.f};
        z = fma2s(lo2(w2a), tanh_fast(accA[i][0]), z);
        z = fma2s(hi2(w2a), tanh_fast(accA[i][1]), z);
        z = fma2s(lo2(w2b), tanh_fast(accA[i][2]), z);
        z = fma2s(hi2(w2b), tanh_fast(accA[i][3]), z);
        z = fma2s(lo2(w2c), tanh_fast(accB[i][0]), z);
        z = fma2s(hi2(w2c), tanh_fast(accB[i][1]), z);
        z = fma2s(lo2(w2d), tanh_fast(accB[i][2]), z);
        z = fma2s(hi2(w2d), tanh_fast(accB[i][3]), z);
        float a = z[0], b = z[1];
        #pragma unroll
        for (int m = 4; m <= 32; m <<= 1) {
          a += __shfl_xor(a, m, 64);
          b += __shfl_xor(b, m, 64);
        }
        z0[i] = a; z1[i] = b;
      }
    }

    // ---- next graph's h0 prefetch (fenced both sides) ----
    __builtin_amdgcn_sched_barrier(0);
    f4 h0b[8];
    const bool more = (si + 1 < SPW) && (g + 1 < G);
    if (more) {
      const float* xn = x + (g + 1) * NPG * HN;
      #pragma unroll
      for (int r = 0; r < 8; ++r)
        h0b[r] = *(const f4*)(xn + (sr + 4 * r) * HN + sc * 4);
    }
    __builtin_amdgcn_sched_barrier(0);

    // ---- softmax + gumbel (replicated across cg; cg==0 writes) ----
    float vSLN = 0.f, vSLN2 = 0.f, vpres = 0.f;
    #pragma unroll
    for (int i = 0; i < 8; ++i) {
      const int n = ng + 4 * i;
      f2 gnr = *(const f2*)(gn + (nb + n) * 2);
      float za = z0[i] + b20, zb = z1[i] + b21;
      float zm = fmaxf(za, zb);
      float e0 = __expf(za - zm), e1 = __expf(zb - zm);
      float a0 = e0 / (e0 + e1), a1 = 1.f - a0;
      float q0 = a0 + gnr[0], q1 = a1 + gnr[1];
      float qm = fmaxf(q0, q1);
      float E0 = __expf(q0 - qm), E1 = __expf(q1 - qm);
      float lp = E0 / (E0 + E1), ln = 1.f - lp;
      if (cg == 0) { s_lp[wv][n] = lp; s_a0[wv][n] = a0; }
      vSLN += ln; vSLN2 += ln * ln; vpres += (a0 > 0.5f) ? 1.f : 0.f;
    }
    vSLN  += __shfl_xor(vSLN, 1, 64);  vSLN  += __shfl_xor(vSLN, 2, 64);
    vSLN2 += __shfl_xor(vSLN2, 1, 64); vSLN2 += __shfl_xor(vSLN2, 2, 64);
    vpres += __shfl_xor(vpres, 1, 64); vpres += __shfl_xor(vpres, 2, 64);

    if (l < NPG)
      out[2 * GL + nb + l] = (s_lp[wv][l] > 0.5f) ? 1.0f : 0.0f;   // active

    // ---- T2 + noisy_emb (x, un from global; packed math) ----
    float tv = 0.f;
    f2 A = {0.f, 0.f}, B = {0.f, 0.f};
    #pragma unroll 8
    for (int n = 0; n < NPG; ++n) {
      f2 xv = *(const f2*)(xg + n * HN + 2 * l);
      f2 uv = *(const f2*)(ug + n * HN + 2 * l);
      float lpn = s_lp[wv][n];
      float lnn = 1.f - lpn;
      f2 d = xv - mu;                  // v_pk_add
      f2 dd = d * d;                   // v_pk_mul
      float se = dd[0] * iv[0] + dd[1] * iv[1];
      tv = fmaf(lpn * lpn, se, tv);
      A = fma2s(xv, lpn, A);           // v_pk_fma
      B = fma2s(uv, lnn, B);           // v_pk_fma
    }
    {
      f2 ne;
      ne[0] = fmaf(mu[0], vSLN, A[0]) + sd[0] * B[0];
      ne[1] = fmaf(mu[1], vSLN, A[1]) + sd[1] * B[1];
      *(f2*)&out[GL + g * HN + 2 * l] = ne;        // noisy_emb
    }
    #pragma unroll
    for (int m = 1; m <= 32; m <<= 1) tv += __shfl_xor(tv, m, 64);

    // ---- edges -> 2x2 adjacency ----
    float c00 = 0.f, c01 = 0.f, c10 = 0.f, c11 = 0.f;
    for (int e = l; e < epg; e += 64) {
      int s2 = ei[g * epg + e] - (int)nb;
      int d2 = ei[E + g * epg + e] - (int)nb;
      float as0 = s_a0[wv][s2], as1 = 1.f - as0;
      float ad0 = s_a0[wv][d2], ad1 = 1.f - ad0;
      c00 = fmaf(as0, ad0, c00); c01 = fmaf(as0, ad1, c01);
      c10 = fmaf(as1, ad0, c10); c11 = fmaf(as1, ad1, c11);
    }
    #pragma unroll
    for (int m = 1; m <= 32; m <<= 1) {
      c00 += __shfl_xor(c00, m, 64); c01 += __shfl_xor(c01, m, 64);
      c10 += __shfl_xor(c10, m, 64); c11 += __shfl_xor(c11, m, 64);
    }
    if (l == 0) {
      float d0 = c00 / fmaxf(fabsf(c00) + fabsf(c01), 1e-12f);
      float d1 = c11 / fmaxf(fabsf(c10) + fabsf(c11), 1e-12f);
      float pen = 0.5f * ((d0 - 1.f) * (d0 - 1.f) + (d1 - 1.f) * (d1 - 1.f));
      float kl = (0.5f * vSLN2 * r2acc + (float)NPG * tv) / (float)(NPG * HN);
      ws[g]                 = kl;
      ws[(size_t)G + g]     = pen;
      ws[2 * (size_t)G + g] = vpres * (1.0f / NPG);
    }

    // ---- stage next graph's h0 ----
    if (more) {
      #pragma unroll
      for (int r = 0; r < 8; ++r)
        *(f4*)&xh[(sr + 4 * r) * SXH + sc * 4] = h0b[r];
    }
  }
}

// deterministic fixed-order reduction of the 3 per-graph scalar arrays
__global__ __launch_bounds__(1024) void gib_final(const float* __restrict__ ws,
                                                  float* __restrict__ out,
                                                  int G, long base)
{
  __shared__ float red[3][16];
  const int t = threadIdx.x, w = t >> 6, lid = t & 63;
  float s0 = 0.f, s1 = 0.f, s2 = 0.f;
  for (int i = t; i < G; i += 1024) {
    s0 += ws[(size_t)G + i];       // pos_penalty
    s1 += ws[i];                   // kl
    s2 += ws[2 * (size_t)G + i];   // preserve
  }
  #pragma unroll
  for (int m = 1; m <= 32; m <<= 1) {
    s0 += __shfl_xor(s0, m, 64);
    s1 += __shfl_xor(s1, m, 64);
    s2 += __shfl_xor(s2, m, 64);
  }
  if (lid == 0) { red[0][w] = s0; red[1][w] = s1; red[2][w] = s2; }
  __syncthreads();
  if (t == 0) {
    float r0 = 0.f, r1 = 0.f, r2 = 0.f;
    for (int i = 0; i < 16; ++i) { r0 += red[0][i]; r1 += red[1][i]; r2 += red[2][i]; }
    out[base + 0] = r0 / (float)G;
    out[base + 1] = r1 / (float)G;
    out[base + 2] = r2 / (float)G;
  }
}

extern "C" void kernel_launch(void* const* d_in, const int* in_sizes, int n_in,
                              void* d_out, int out_size, void* d_ws, size_t ws_size,
                              hipStream_t stream)
{
  const float* x  = (const float*)d_in[0];
  const float* W1 = (const float*)d_in[1];
  const float* b1 = (const float*)d_in[2];
  const float* W2 = (const float*)d_in[3];
  const float* b2 = (const float*)d_in[4];
  const float* gn = (const float*)d_in[5];
  const float* un = (const float*)d_in[6];
  const int*   ei = (const int*)d_in[7];
  float* out = (float*)d_out;
  float* ws  = (float*)d_ws;

  const long N = (long)in_sizes[0] / HN;
  const int  G = (int)(N / NPG);
  const long E = (long)in_sizes[7] / 2;
  const int epg = (int)(E / G);

  const int nblocks = (G + NW * SPW - 1) / (NW * SPW);   // 32768/64 = 512
  hipLaunchKernelGGL(gib_main, dim3(nblocks), dim3(NT), 0, stream,
                     x, W1, b1, W2, b2, gn, un, ei, out, ws, G, E, epg);
  const long base = 2L * (long)G * HN + N;
  hipLaunchKernelGGL(gib_final, dim3(1), dim3(1024), 0, stream, ws, out, G, base);
}